// Round 1
// baseline (1273.830 us; speedup 1.0000x reference)
//
#include <hip/hip_runtime.h>

// Problem constants (match reference)
#define LSEQ   16384
#define NB     20
#define NBATCH 128
#define TAPS   513
#define P      512           // padlen == TAPS-1
#define LE     (LSEQ + 2*P)  // 17408, ext length

// Tiling
#define TO   1024            // outputs per block
#define BS   128             // threads per block
#define EXTN (TO + 2*P)      // 2048 ext values per tile
#define YN   (TO + P)        // 1536 y values per tile
#define KLP  520             // kernel taps padded to multiple of 4 (+zeros)
#define YLP  (YN + 8)        // y tile + zero guard (and 16B-align pad)

// LDS layout (single array so out-of-range-by-design prefetches stay in-bounds):
//   [0, KLP)                      : kl   (taps, zero-padded)
//   [KLP, KLP+YLP)                : yl   (y tile; [YN, YN+8) zero guard)
//   [KLP+YLP, KLP+YLP+4)          : ext guard (zeros), extl[-4..-1]
//   [KLP+YLP+4, ... +4+EXTN)      : extl (ext tile)
#define SMEM_FLOATS (KLP + YLP + 4 + EXTN)

__global__ __launch_bounds__(BS) void bandpass_filtfilt_kernel(
    const float* __restrict__ x,   // (B, L)
    const float* __restrict__ Kg,  // (NB, TAPS)
    float* __restrict__ out)       // (B, NB, L)
{
    __shared__ __align__(16) float smem[SMEM_FLOATS];
    __shared__ int s_taps;

    float* kl   = smem;
    float* yl   = smem + KLP;            // offset 520 floats -> 16B aligned
    float* extl = smem + KLP + YLP + 4;  // offset 2068 floats = 8272 B -> 16B aligned

    const int tid  = threadIdx.x;
    const int tile = blockIdx.x;
    const int band = blockIdx.y;
    const int b    = blockIdx.z;
    const int t0   = tile * TO;

    if (tid == 0) s_taps = 4;  // at least one group
    __syncthreads();

    // ---- Phase 0: load taps (track last nonzero), zero guards, stage ext ----
    int last = 0;
    for (int idx = tid; idx < KLP; idx += BS) {
        float v = (idx < TAPS) ? Kg[band * TAPS + idx] : 0.f;
        kl[idx] = v;
        if (v != 0.f) last = idx + 1;
    }
    atomicMax(&s_taps, last);

    if (tid < 4) extl[tid - 4] = 0.f;     // ext low guard
    if (tid < 8) yl[YN + tid] = 0.f;      // y high guard

    const float* xb = x + (size_t)b * LSEQ;
    const float x0 = xb[0];
    const float xN = xb[LSEQ - 1];
    for (int e = tid; e < EXTN; e += BS) {
        int g = t0 + e;  // global ext index, in [0, LE)
        float v;
        if (g < P)              v = 2.f * x0 - xb[P - g];
        else if (g < P + LSEQ)  v = xb[g - P];
        else                    v = 2.f * xN - xb[2 * LSEQ + P - 2 - g];
        extl[e] = v;
    }
    __syncthreads();

    const int taps = s_taps;
    const int G = (taps + 3) >> 2;  // groups of 4 taps; zero-padded tail is safe

    const float4* kl4   = (const float4*)kl;
    const float4* extl4 = (const float4*)extl;
    const float4* yl4   = (const float4*)yl;

    // ---- Pass 1: y[m] = sum_i kl[i] * extl[m + P - i],  m in [0, YN) ----
    // window descends in ext as i ascends; 4 outputs/thread, 8-float reg window
    for (int m0 = 4 * tid; m0 < YN; m0 += 4 * BS) {
        int q = (m0 + P) >> 2;
        float4 whi = extl4[q];
        float4 wlo = extl4[q - 1];
        float a0 = 0.f, a1 = 0.f, a2 = 0.f, a3 = 0.f;
        for (int g = 0; g < G; ++g) {
            float4 kq = kl4[g];  // broadcast (uniform) read
            a0 = fmaf(kq.x, whi.x, a0); a1 = fmaf(kq.x, whi.y, a1); a2 = fmaf(kq.x, whi.z, a2); a3 = fmaf(kq.x, whi.w, a3);
            a0 = fmaf(kq.y, wlo.w, a0); a1 = fmaf(kq.y, whi.x, a1); a2 = fmaf(kq.y, whi.y, a2); a3 = fmaf(kq.y, whi.z, a3);
            a0 = fmaf(kq.z, wlo.z, a0); a1 = fmaf(kq.z, wlo.w, a1); a2 = fmaf(kq.z, whi.x, a2); a3 = fmaf(kq.z, whi.y, a3);
            a0 = fmaf(kq.w, wlo.y, a0); a1 = fmaf(kq.w, wlo.z, a1); a2 = fmaf(kq.w, wlo.w, a2); a3 = fmaf(kq.w, whi.x, a3);
            whi = wlo;
            wlo = extl4[q - 2 - g];  // prefetch next; min index -2 lands in yl zero guard (valid LDS)
        }
        *(float4*)&yl[m0] = make_float4(a0, a1, a2, a3);
    }
    __syncthreads();

    // ---- Pass 2: out[t] = sum_j kl[j] * yl[t + j],  t in [0, TO) ----
    float* outb = out + ((size_t)b * NB + band) * LSEQ + t0;
    for (int lt0 = 4 * tid; lt0 < TO; lt0 += 4 * BS) {
        int q = lt0 >> 2;
        float4 wlo = yl4[q];
        float4 whi = yl4[q + 1];
        float a0 = 0.f, a1 = 0.f, a2 = 0.f, a3 = 0.f;
        for (int g = 0; g < G; ++g) {
            float4 kq = kl4[g];
            a0 = fmaf(kq.x, wlo.x, a0); a1 = fmaf(kq.x, wlo.y, a1); a2 = fmaf(kq.x, wlo.z, a2); a3 = fmaf(kq.x, wlo.w, a3);
            a0 = fmaf(kq.y, wlo.y, a0); a1 = fmaf(kq.y, wlo.z, a1); a2 = fmaf(kq.y, wlo.w, a2); a3 = fmaf(kq.y, whi.x, a3);
            a0 = fmaf(kq.z, wlo.z, a0); a1 = fmaf(kq.z, wlo.w, a1); a2 = fmaf(kq.z, whi.x, a2); a3 = fmaf(kq.z, whi.y, a3);
            a0 = fmaf(kq.w, wlo.w, a0); a1 = fmaf(kq.w, whi.x, a1); a2 = fmaf(kq.w, whi.y, a2); a3 = fmaf(kq.w, whi.z, a3);
            wlo = whi;
            whi = yl4[q + 2 + g];  // prefetch next; max index 385 -> yl zero guard (in-bounds)
        }
        *(float4*)&outb[lt0] = make_float4(a0, a1, a2, a3);
    }
}

extern "C" void kernel_launch(void* const* d_in, const int* in_sizes, int n_in,
                              void* d_out, int out_size, void* d_ws, size_t ws_size,
                              hipStream_t stream) {
    const float* x  = (const float*)d_in[0];  // (128, 1, 16384) fp32
    const float* Kg = (const float*)d_in[1];  // (20, 513) fp32
    // d_in[2] = padlen (512), hardcoded as P
    float* out = (float*)d_out;               // (128, 1, 20, 16384) fp32

    dim3 grid(LSEQ / TO, NB, NBATCH);  // (16, 20, 128)
    dim3 block(BS);
    bandpass_filtfilt_kernel<<<grid, block, 0, stream>>>(x, Kg, out);
}

// Round 2
// 653.108 us; speedup vs baseline: 1.9504x; 1.9504x over previous
//
#include <hip/hip_runtime.h>

// Problem constants
#define LSEQ   16384
#define NB     20
#define NBATCH 128
#define TAPS   513
#define P      512
#define CT     (2*TAPS - 1)   // 1025 combined (autocorrelation) taps

// Tiling
#define TO     1024           // outputs per block
#define BS     128            // threads per block (8 outputs/thread, exactly one pass)
#define EXTN   (TO + 2*P)     // 2048 ext floats per tile (window span = 1025)
#define CLP    1040           // C taps padded (quad reads up to float 1031)
#define EXTLP  2320           // swizzled ext storage: 2064 logical + swizzle expansion
#define SMEMF  (CLP + EXTLP)

// Swizzle: logical float index f stored at f + 4*(f>>5)  (insert one quad gap
// every 8 quads). Makes lane-stride-2-quad b128 reads cover all 32 banks.
__device__ __forceinline__ int swz(int f) { return f + ((f >> 5) << 2); }
__device__ __forceinline__ const float4* qptr(const float* base, int q) {
    return (const float4*)(base + 4 * q + ((q >> 3) << 2));
}

// ---- Pre-kernel: C[band][d] = sum_i k[i]*k[i+d-512] (autocorrelation) ----
__global__ void autocorr_kernel(const float* __restrict__ Kg, float* __restrict__ C) {
    __shared__ float kk[TAPS];
    const int band = blockIdx.x;
    for (int i = threadIdx.x; i < TAPS; i += blockDim.x) kk[i] = Kg[band * TAPS + i];
    __syncthreads();
    int d = blockIdx.y * 256 + threadIdx.x;
    if (d < CT) {
        int l = d - (TAPS - 1);
        int al = l < 0 ? -l : l;
        float s = 0.f;
        for (int i = 0; i + al < TAPS; ++i) s = fmaf(kk[i], kk[i + al], s);
        C[band * CT + d] = s;
    }
}

// ---- Main kernel: out[t] = sum_{u=0}^{1024} C[u] * ext[t + u] ----
__global__ __launch_bounds__(BS) void filtfilt_kernel(
    const float* __restrict__ x,   // (B, L)
    const float* __restrict__ C,   // (NB, CT) from d_ws
    float* __restrict__ out)       // (B, NB, L)
{
    __shared__ __align__(16) float smem[SMEMF];
    __shared__ int s_first, s_last;

    float* Cl   = smem;        // CLP floats (16B-aligned: 1040*4 bytes)
    float* extl = smem + CLP;  // swizzled ext tile

    const int tid  = threadIdx.x;
    const int tile = blockIdx.x;
    const int band = blockIdx.y;
    const int b    = blockIdx.z;
    const int t0   = tile * TO;

    if (tid == 0) { s_first = CT - 1; s_last = 0; }
    __syncthreads();

    // Load C taps, detect nonzero range (skip zero head AND tail per band)
    int fst = 1 << 20, lst = 0;
    for (int idx = tid; idx < CLP; idx += BS) {
        float v = (idx < CT) ? C[band * CT + idx] : 0.f;
        Cl[idx] = v;
        if (v != 0.f) { if (idx < fst) fst = idx; if (idx > lst) lst = idx; }
    }
    atomicMin(&s_first, fst);
    atomicMax(&s_last, lst);

    // Zero guard for window prefetch overshoot (logical floats [EXTN, EXTN+16))
    if (tid < 16) extl[swz(EXTN + tid)] = 0.f;

    // Stage ext tile (odd-extension of x), swizzled store
    const float* xb = x + (size_t)b * LSEQ;
    const float x0 = xb[0];
    const float xN = xb[LSEQ - 1];
    for (int e = tid; e < EXTN; e += BS) {
        int g = t0 + e;
        float v;
        if (g < P)              v = 2.f * x0 - xb[P - g];
        else if (g < P + LSEQ)  v = xb[g - P];
        else                    v = 2.f * xN - xb[2 * LSEQ + P - 2 - g];
        extl[swz(e)] = v;
    }
    __syncthreads();

    const int g0 = s_first >> 2;
    const int g1 = s_last >> 2;
    const float4* Cl4 = (const float4*)Cl;

    // 8 consecutive outputs per thread; 12-float register window over ext
    const int qb = 2 * tid + g0;  // logical quad of extl at window start
    float4 w0 = *qptr(extl, qb);
    float4 w1 = *qptr(extl, qb + 1);
    float4 w2 = *qptr(extl, qb + 2);
    float4 cq = Cl4[g0];
    float a0 = 0.f, a1 = 0.f, a2 = 0.f, a3 = 0.f, a4 = 0.f, a5 = 0.f, a6 = 0.f, a7 = 0.f;

    for (int g = g0; g <= g1; ++g) {
        float4 cn = Cl4[g + 1];                 // prefetch taps (broadcast)
        float4 w3 = *qptr(extl, qb + (g - g0) + 3);  // prefetch window quad
        // a_r += cq[j] * f[r+j],  f = [w0|w1|w2] (12 floats, f[0..10] used)
        a0 = fmaf(cq.x, w0.x, a0); a1 = fmaf(cq.x, w0.y, a1); a2 = fmaf(cq.x, w0.z, a2); a3 = fmaf(cq.x, w0.w, a3);
        a4 = fmaf(cq.x, w1.x, a4); a5 = fmaf(cq.x, w1.y, a5); a6 = fmaf(cq.x, w1.z, a6); a7 = fmaf(cq.x, w1.w, a7);
        a0 = fmaf(cq.y, w0.y, a0); a1 = fmaf(cq.y, w0.z, a1); a2 = fmaf(cq.y, w0.w, a2); a3 = fmaf(cq.y, w1.x, a3);
        a4 = fmaf(cq.y, w1.y, a4); a5 = fmaf(cq.y, w1.z, a5); a6 = fmaf(cq.y, w1.w, a6); a7 = fmaf(cq.y, w2.x, a7);
        a0 = fmaf(cq.z, w0.z, a0); a1 = fmaf(cq.z, w0.w, a1); a2 = fmaf(cq.z, w1.x, a2); a3 = fmaf(cq.z, w1.y, a3);
        a4 = fmaf(cq.z, w1.z, a4); a5 = fmaf(cq.z, w1.w, a5); a6 = fmaf(cq.z, w2.x, a6); a7 = fmaf(cq.z, w2.y, a7);
        a0 = fmaf(cq.w, w0.w, a0); a1 = fmaf(cq.w, w1.x, a1); a2 = fmaf(cq.w, w1.y, a2); a3 = fmaf(cq.w, w1.z, a3);
        a4 = fmaf(cq.w, w1.w, a4); a5 = fmaf(cq.w, w2.x, a5); a6 = fmaf(cq.w, w2.y, a6); a7 = fmaf(cq.w, w2.z, a7);
        w0 = w1; w1 = w2; w2 = w3; cq = cn;
    }

    float* outb = out + ((size_t)b * NB + band) * LSEQ + t0 + 8 * tid;
    *(float4*)outb       = make_float4(a0, a1, a2, a3);
    *(float4*)(outb + 4) = make_float4(a4, a5, a6, a7);
}

extern "C" void kernel_launch(void* const* d_in, const int* in_sizes, int n_in,
                              void* d_out, int out_size, void* d_ws, size_t ws_size,
                              hipStream_t stream) {
    const float* x  = (const float*)d_in[0];  // (128, 1, 16384) fp32
    const float* Kg = (const float*)d_in[1];  // (20, 513) fp32
    float* out = (float*)d_out;               // (128, 1, 20, 16384) fp32
    float* C   = (float*)d_ws;                // (20, 1025) fp32 scratch

    autocorr_kernel<<<dim3(NB, 5), dim3(256), 0, stream>>>(Kg, C);
    filtfilt_kernel<<<dim3(LSEQ / TO, NB, NBATCH), dim3(BS), 0, stream>>>(x, C, out);
}

// Round 3
// 296.735 us; speedup vs baseline: 4.2928x; 2.2010x over previous
//
#include <hip/hip_runtime.h>

// Problem constants
#define LSEQ   16384
#define NB     20
#define NBATCH 128
#define TAPS   513
#define CT     (2*TAPS - 1)   // 1025 combined (autocorrelation) taps
#define MAXSTEP 68            // max k-steps per band: (1024/16 + 3) = 67 -> pad to 68
#define STRIDE 3076           // ushorts per batch row in LDS (3072 span + 4 stagger)
#define SPAN   3072           // ext elems needed per 2048-output tile
#define LDSN   (8*STRIDE + 16) // + tail pad for harmless last-iteration prefetch

// ws layout (bytes)
#define CF_OFF   0            // fp32 C: 20*1025*4 = 82000 B
#define HDR_OFF  82944        // int2 per band: {koff_min, nsteps}
#define ATAB_OFF 84480        // bf16 A-fragment table: 20*68*64*16 B = 1.39 MB

typedef short  v8s  __attribute__((ext_vector_type(8)));
typedef __bf16 v8bf __attribute__((ext_vector_type(8)));
typedef float  v16f __attribute__((ext_vector_type(16)));

__device__ __forceinline__ unsigned short f2bf(float f) {  // RNE fp32->bf16
    union { float f; unsigned u; } v; v.f = f;
    return (unsigned short)((v.u + 0x7fffu + ((v.u >> 16) & 1u)) >> 16);
}

__device__ __forceinline__ v16f vzero() {
    v16f z;
    #pragma unroll
    for (int i = 0; i < 16; ++i) z[i] = 0.f;
    return z;
}

__device__ __forceinline__ v8bf ldB(const unsigned short* p) {
    ushort4 lo = *(const ushort4*)p;        // ds_read 8B (8B-aligned by construction)
    ushort4 hi = *(const ushort4*)(p + 4);
    v8s r;
    r[0]=(short)lo.x; r[1]=(short)lo.y; r[2]=(short)lo.z; r[3]=(short)lo.w;
    r[4]=(short)hi.x; r[5]=(short)hi.y; r[6]=(short)hi.z; r[7]=(short)hi.w;
    return __builtin_bit_cast(v8bf, r);
}

// ---- Pre 1: C[band][d] = autocorrelation of taps (fp32) ----
__global__ void autocorr_kernel(const float* __restrict__ Kg, float* __restrict__ Cf) {
    __shared__ float kk[TAPS];
    const int band = blockIdx.x;
    for (int i = threadIdx.x; i < TAPS; i += blockDim.x) kk[i] = Kg[band * TAPS + i];
    __syncthreads();
    int d = blockIdx.y * 256 + threadIdx.x;
    if (d < CT) {
        int l = d - (TAPS - 1);
        int al = l < 0 ? -l : l;
        float s = 0.f;
        for (int i = 0; i + al < TAPS; ++i) s = fmaf(kk[i], kk[i + al], s);
        Cf[band * CT + d] = s;
    }
}

// ---- Pre 2: per-band nonzero range -> {koff_min, nsteps} ----
__global__ void hdr_kernel(const float* __restrict__ Cf, int2* __restrict__ hdr) {
    __shared__ int smin, smax;
    const int band = blockIdx.x;
    if (threadIdx.x == 0) { smin = CT; smax = 0; }
    __syncthreads();
    int lmin = CT, lmax = 0;
    for (int d = threadIdx.x; d < CT; d += 256)
        if (Cf[band * CT + d] != 0.f) { if (d < lmin) lmin = d; if (d > lmax) lmax = d; }
    atomicMin(&smin, lmin);
    atomicMax(&smax, lmax);
    __syncthreads();
    if (threadIdx.x == 0) {
        int k0 = smin & ~15;                 // lowest koff (m=0,k=0 covers u0)
        int k1 = ((smax + 31) >> 4) << 4;    // highest koff (m=31,k=15 covers u1)
        int2 h; h.x = k0; h.y = (k1 - k0) / 16 + 1;  // nsteps <= 66
        hdr[band] = h;
    }
}

// ---- Pre 3: A-fragment table. A[m][k] = C[koff + k - m], per-lane 8 bf16 ----
__global__ void atab_kernel(const float* __restrict__ Cf, const int2* __restrict__ hdr,
                            short* __restrict__ atab) {
    const int s = blockIdx.x, band = blockIdx.y;
    const int lane = threadIdx.x;            // 64
    const int m = lane & 31, kh = lane >> 5;
    const int koff = hdr[band].x + 16 * s;
    v8s r;
    #pragma unroll
    for (int j = 0; j < 8; ++j) {
        int ci = koff + 8 * kh + j - m;
        float v = (ci >= 0 && ci < CT) ? Cf[band * CT + ci] : 0.f;
        r[j] = (short)f2bf(v);
    }
    *(v8s*)(atab + ((size_t)(band * MAXSTEP + s) * 64 + lane) * 8) = r;
}

// ---- Main: out[t] = sum_u C[u]*ext[t+u] via 32x32x16 bf16 MFMA ----
// Block: 8 batches x 2048 times, 4 waves. Wave w: times [512w, 512w+512).
// MFMA tile: m = time%32, n = (brow in 8 batches) + 8*(tb in 4 time-subtiles).
__global__ __launch_bounds__(256, 3) void filt_mfma(
    const float* __restrict__ x, const short* __restrict__ atab,
    const int2* __restrict__ hdr, float* __restrict__ out)
{
    __shared__ unsigned short extl[LDSN];
    const int tid = threadIdx.x;
    const int tg = blockIdx.x, band = blockIdx.y, bg = blockIdx.z;
    const int T0 = tg * 2048;
    const int2 hh = hdr[band];               // uniform scalar load
    const int koffmin = hh.x, N = hh.y;

    // Stage odd-extended x as bf16, 8 batch rows
    for (int b = 0; b < 8; ++b) {
        const float* xb = x + (size_t)(bg * 8 + b) * LSEQ;
        const float x0 = xb[0], xN = xb[LSEQ - 1];
        for (int e4 = tid; e4 < SPAN / 4; e4 += 256) {
            const int e = 4 * e4;
            const int g0 = T0 + e;           // index into extfull [0, 17408)
            float v0, v1, v2, v3;
            if (g0 >= 512 && g0 + 4 <= 16896) {
                float4 xv = *(const float4*)(xb + (g0 - 512));
                v0 = xv.x; v1 = xv.y; v2 = xv.z; v3 = xv.w;
            } else {
                float vv[4];
                #pragma unroll
                for (int t = 0; t < 4; ++t) {
                    int g = g0 + t;
                    vv[t] = (g < 512)    ? 2.f * x0 - xb[512 - g]
                          : (g < 16896)  ? xb[g - 512]
                          :                2.f * xN - xb[33278 - g];
                }
                v0 = vv[0]; v1 = vv[1]; v2 = vv[2]; v3 = vv[3];
            }
            ushort4 q = make_ushort4(f2bf(v0), f2bf(v1), f2bf(v2), f2bf(v3));
            *(ushort4*)&extl[b * STRIDE + e] = q;
        }
    }
    __syncthreads();

    const int lane = tid & 63;
    const int w    = tid >> 6;               // wave 0..3
    const int n    = lane & 31, kh = lane >> 5;
    const int brow = n & 7,  tb = n >> 3;
    const unsigned short* bp = extl + brow * STRIDE + 512 * w + 32 * tb + 8 * kh + koffmin;
    const short* ap = atab + ((size_t)(band * MAXSTEP) * 64 + lane) * 8;  // step stride 512 shorts

    v16f ac0 = vzero(), ac1 = vzero(), ac2 = vzero(), ac3 = vzero();
    v8bf A  = *(const v8bf*)ap;
    v8bf B0 = ldB(bp);
    v8bf B1 = ldB(bp + 128);
    v8bf B2 = ldB(bp + 256);
    v8bf B3 = ldB(bp + 384);

    for (int s = 0; s < N; ++s) {
        // prefetch next step (table has >= N+1 entries; LDS tail pad covers B overshoot)
        const v8bf An = *(const v8bf*)(ap + (size_t)(s + 1) * 512);
        const unsigned short* bpn = bp + 16 * (s + 1);
        v8bf Bn0 = ldB(bpn);
        v8bf Bn1 = ldB(bpn + 128);
        v8bf Bn2 = ldB(bpn + 256);
        v8bf Bn3 = ldB(bpn + 384);
        ac0 = __builtin_amdgcn_mfma_f32_32x32x16_bf16(A, B0, ac0, 0, 0, 0);
        ac1 = __builtin_amdgcn_mfma_f32_32x32x16_bf16(A, B1, ac1, 0, 0, 0);
        ac2 = __builtin_amdgcn_mfma_f32_32x32x16_bf16(A, B2, ac2, 0, 0, 0);
        ac3 = __builtin_amdgcn_mfma_f32_32x32x16_bf16(A, B3, ac3, 0, 0, 0);
        A = An; B0 = Bn0; B1 = Bn1; B2 = Bn2; B3 = Bn3;
    }

    // Epilogue: D[m][n] -> out. row = (reg&3) + 8*(reg>>2) + 4*(lane>>5)
    float* ob = out + ((size_t)(bg * 8 + brow) * NB + band) * LSEQ
                    + T0 + 512 * w + 32 * tb + 4 * kh;
    #pragma unroll
    for (int q = 0; q < 4; ++q) {
        *(float4*)(ob +       8 * q) = make_float4(ac0[4*q], ac0[4*q+1], ac0[4*q+2], ac0[4*q+3]);
        *(float4*)(ob + 128 + 8 * q) = make_float4(ac1[4*q], ac1[4*q+1], ac1[4*q+2], ac1[4*q+3]);
        *(float4*)(ob + 256 + 8 * q) = make_float4(ac2[4*q], ac2[4*q+1], ac2[4*q+2], ac2[4*q+3]);
        *(float4*)(ob + 384 + 8 * q) = make_float4(ac3[4*q], ac3[4*q+1], ac3[4*q+2], ac3[4*q+3]);
    }
}

extern "C" void kernel_launch(void* const* d_in, const int* in_sizes, int n_in,
                              void* d_out, int out_size, void* d_ws, size_t ws_size,
                              hipStream_t stream) {
    const float* x  = (const float*)d_in[0];  // (128, 1, 16384) fp32
    const float* Kg = (const float*)d_in[1];  // (20, 513) fp32
    float* out = (float*)d_out;               // (128, 1, 20, 16384) fp32

    char* wsb = (char*)d_ws;
    float* Cf  = (float*)(wsb + CF_OFF);
    int2*  hdr = (int2*)(wsb + HDR_OFF);
    short* atab = (short*)(wsb + ATAB_OFF);

    autocorr_kernel<<<dim3(NB, 5), dim3(256), 0, stream>>>(Kg, Cf);
    hdr_kernel<<<dim3(NB), dim3(256), 0, stream>>>(Cf, hdr);
    atab_kernel<<<dim3(MAXSTEP, NB), dim3(64), 0, stream>>>(Cf, hdr, atab);
    filt_mfma<<<dim3(LSEQ / 2048, NB, NBATCH / 8), dim3(256), 0, stream>>>(x, atab, hdr, out);
}

// Round 4
// 287.813 us; speedup vs baseline: 4.4259x; 1.0310x over previous
//
#include <hip/hip_runtime.h>

// Problem constants
#define LSEQ   16384
#define NB     20
#define NBATCH 128
#define TAPS   513
#define CT     (2*TAPS - 1)   // 1025 combined (autocorrelation) taps
#define MAXSTEP 68            // k-step table entries per band (N+2 <= 68)

// Main-kernel tiling
#define TT     1024           // output times per block
#define SPANE  2064           // staged ext ushorts per batch row (TT + 1024 + 16 prefetch pad)
#define STRIDE 2072           // row stride in ushorts: 16B-aligned, +8 bank stagger
#define EXTEND 16896          // 512 + LSEQ
#define GMAX   17407          // last valid ext index (LSEQ + 2*512 - 1)

// ws layout (bytes)
#define HDR_OFF  0            // int2 per band {k0, nsteps}: 160 B
#define ATAB_OFF 1024         // bf16 A-fragment table: 20*68*64*16 B = 1.39 MB

typedef short  v8s  __attribute__((ext_vector_type(8)));
typedef __bf16 v8bf __attribute__((ext_vector_type(8)));
typedef float  v16f __attribute__((ext_vector_type(16)));

__device__ __forceinline__ unsigned short f2bf(float f) {  // RNE fp32->bf16
    union { float f; unsigned u; } v; v.f = f;
    return (unsigned short)((v.u + 0x7fffu + ((v.u >> 16) & 1u)) >> 16);
}

__device__ __forceinline__ v16f vzero() {
    v16f z;
    #pragma unroll
    for (int i = 0; i < 16; ++i) z[i] = 0.f;
    return z;
}

// ---- Fused pre-kernel: autocorr -> nonzero range -> A-fragment table ----
// One block per band. A[m][k] = C[k0 + 16s + k - m] as per-lane 8 bf16.
__global__ __launch_bounds__(256) void prep_kernel(
    const float* __restrict__ Kg, int2* __restrict__ hdr, short* __restrict__ atab)
{
    __shared__ float kk[TAPS];
    __shared__ float Cs[CT];
    __shared__ int smin, smax, sk0, sN;
    const int band = blockIdx.x;
    const int tid  = threadIdx.x;

    for (int i = tid; i < TAPS; i += 256) kk[i] = Kg[band * TAPS + i];
    if (tid == 0) { smin = CT; smax = 0; }
    __syncthreads();

    int lmin = CT, lmax = 0;
    for (int d = tid; d < CT; d += 256) {
        int al = d - 512; if (al < 0) al = -al;
        float s = 0.f;
        for (int i = 0; i + al < TAPS; ++i) s = fmaf(kk[i], kk[i + al], s);
        Cs[d] = s;
        if (s != 0.f) { if (d < lmin) lmin = d; if (d > lmax) lmax = d; }
    }
    atomicMin(&smin, lmin);
    atomicMax(&smax, lmax);
    __syncthreads();

    if (tid == 0) {
        int k0 = smin & ~15;
        int k1 = ((smax + 31) >> 4) << 4;
        int N  = (k1 - k0) / 16 + 1;            // <= 66
        int2 h; h.x = k0; h.y = N;
        hdr[band] = h;
        sk0 = k0; sN = N;
    }
    __syncthreads();

    const int k0 = sk0, N = sN;
    for (int idx = tid; idx < (N + 2) * 64; idx += 256) {
        int s = idx >> 6, lane = idx & 63;
        int m = lane & 31, kh = lane >> 5;
        int base = k0 + 16 * s + 8 * kh - m;
        v8s r;
        #pragma unroll
        for (int j = 0; j < 8; ++j) {
            int ci = base + j;
            float v = (ci >= 0 && ci < CT) ? Cs[ci] : 0.f;
            r[j] = (short)f2bf(v);
        }
        *(v8s*)(atab + ((size_t)(band * MAXSTEP + s) * 64 + lane) * 8) = r;
    }
}

// ---- Main kernel: stage ext once, sweep a band group, MFMA 32x32x16 ----
// Block: 8 batches x 1024 times, 4 waves (wave w: times [256w, 256w+256)).
// Wave tile: m = fine time (32), n = brow + 8*tb (8 batches x 4 time-subtiles
// of 32); 2 accumulators at time offsets 0 / 128.
__global__ __launch_bounds__(256, 4) void filt_main(
    const float* __restrict__ x, const short* __restrict__ atab,
    const int2* __restrict__ hdr, float* __restrict__ out)
{
    __shared__ __align__(16) unsigned short extl[8 * STRIDE];
    const int tid = threadIdx.x;
    const int tile = blockIdx.x, grp = blockIdx.y, bg = blockIdx.z;
    const int T0 = tile * TT;

    // ---- Stage odd-extended x as bf16 (8 batch rows, SPANE each) ----
    const bool edge = (T0 < 512) || (T0 + SPANE > EXTEND);
    for (int b = 0; b < 8; ++b) {
        const float* xb = x + (size_t)(bg * 8 + b) * LSEQ;
        float x0 = 0.f, xN = 0.f;
        if (edge) { x0 = xb[0]; xN = xb[LSEQ - 1]; }
        for (int e4 = tid; e4 < SPANE / 4; e4 += 256) {
            const int e = 4 * e4;
            const int g0 = T0 + e;
            float v0, v1, v2, v3;
            if (g0 >= 512 && g0 + 4 <= EXTEND) {
                float4 xv = *(const float4*)(xb + (g0 - 512));
                v0 = xv.x; v1 = xv.y; v2 = xv.z; v3 = xv.w;
            } else {
                float vv[4];
                #pragma unroll
                for (int t = 0; t < 4; ++t) {
                    int g = g0 + t; if (g > GMAX) g = GMAX;  // prefetch pad, never read
                    vv[t] = (g < 512)    ? 2.f * x0 - xb[512 - g]
                          : (g < EXTEND) ? xb[g - 512]
                          :                2.f * xN - xb[2 * LSEQ + 512 - 2 - g];
                }
                v0 = vv[0]; v1 = vv[1]; v2 = vv[2]; v3 = vv[3];
            }
            ushort4 q = make_ushort4(f2bf(v0), f2bf(v1), f2bf(v2), f2bf(v3));
            *(ushort4*)&extl[b * STRIDE + e] = q;
        }
    }
    __syncthreads();

    const int lane = tid & 63;
    const int w    = tid >> 6;
    const int n    = lane & 31, kh = lane >> 5;
    const int brow = n & 7,  tb = n >> 3;
    const unsigned short* bpb = extl + brow * STRIDE + 256 * w + 32 * tb + 8 * kh;

    // Load-balanced band groups (sum of k-steps ~66-84 per group)
    const int g_start[6] = {0, 4, 8, 11, 15, 20};
    const int g_list[20] = {0,19,18,17, 1,16,15,14, 2,3,13, 4,5,6,12, 7,8,9,10,11};

    for (int bi = g_start[grp]; bi < g_start[grp + 1]; ++bi) {
        const int band = g_list[bi];
        const int2 hh = hdr[band];
        const int k0 = hh.x, N = hh.y;
        const unsigned short* bp = bpb + k0;
        const short* ap = atab + (size_t)(band * MAXSTEP) * 512 + lane * 8;

        v16f ac0 = vzero(), ac1 = vzero();
        v8bf A0 = __builtin_bit_cast(v8bf, *(const v8s*)ap);
        v8bf A1 = __builtin_bit_cast(v8bf, *(const v8s*)(ap + 512));
        v8bf B0 = *(const v8bf*)bp;
        v8bf B1 = *(const v8bf*)(bp + 128);

        for (int s = 0; s < N; ++s) {
            v8bf An  = __builtin_bit_cast(v8bf, *(const v8s*)(ap + (size_t)(s + 2) * 512));
            v8bf Bn0 = *(const v8bf*)(bp + 16 * (s + 1));
            v8bf Bn1 = *(const v8bf*)(bp + 128 + 16 * (s + 1));
            ac0 = __builtin_amdgcn_mfma_f32_32x32x16_bf16(A0, B0, ac0, 0, 0, 0);
            ac1 = __builtin_amdgcn_mfma_f32_32x32x16_bf16(A0, B1, ac1, 0, 0, 0);
            A0 = A1; A1 = An; B0 = Bn0; B1 = Bn1;
        }

        // Epilogue: D row = (reg&3) + 8*(reg>>2) + 4*kh  (m = fine time)
        float* ob = out + ((size_t)(bg * 8 + brow) * NB + band) * LSEQ
                        + T0 + 256 * w + 32 * tb + 4 * kh;
        #pragma unroll
        for (int q = 0; q < 4; ++q) {
            *(float4*)(ob +       8 * q) = make_float4(ac0[4*q], ac0[4*q+1], ac0[4*q+2], ac0[4*q+3]);
            *(float4*)(ob + 128 + 8 * q) = make_float4(ac1[4*q], ac1[4*q+1], ac1[4*q+2], ac1[4*q+3]);
        }
    }
}

extern "C" void kernel_launch(void* const* d_in, const int* in_sizes, int n_in,
                              void* d_out, int out_size, void* d_ws, size_t ws_size,
                              hipStream_t stream) {
    const float* x  = (const float*)d_in[0];  // (128, 1, 16384) fp32
    const float* Kg = (const float*)d_in[1];  // (20, 513) fp32
    float* out = (float*)d_out;               // (128, 1, 20, 16384) fp32

    char* wsb = (char*)d_ws;
    int2*  hdr  = (int2*)(wsb + HDR_OFF);
    short* atab = (short*)(wsb + ATAB_OFF);

    prep_kernel<<<dim3(NB), dim3(256), 0, stream>>>(Kg, hdr, atab);
    filt_main<<<dim3(LSEQ / TT, 5, NBATCH / 8), dim3(256), 0, stream>>>(x, atab, hdr, out);
}